// Round 9
// baseline (420.449 us; speedup 1.0000x reference)
//
#include <hip/hip_runtime.h>
#include <math.h>

// Problem constants (from reference)
#define NPATCH 8192
#define KC     10
#define DIN    1024
#define DH     512
#define DA     256
#define NCLS   4

typedef unsigned short u16;
typedef short bf16x8 __attribute__((ext_vector_type(8)));   // 8 bf16 = 4 VGPRs
typedef float f32x4  __attribute__((ext_vector_type(4)));

// Workspace layout (bytes)
#define OFF_CNT   0                  // int[KC] (40B)
#define OFF_BAR   48                 // int[8] barriers: mega 0..2, tail 3..5
#define OFF_IDX   128                // int[KC*NPATCH]
#define OFF_PSUM  327808             // float[KC*DH]
#define OFF_H     348288             // float[KC*DH]
#define OFF_H2    368768             // float[DA]
#define OFF_SRED  369792             // float[64*16]
#define OFF_W1P   373888             // u16[KC*32 panels][512][32] (granule-XOR packed)
#define OFF_W2P   10859648           // u16[KC*16 panels][512][32]
#define OFF_XC    16102528           // u16[8192][1024] bf16 x, COMPACT bucket order
#define OFF_H1    32879744           // u16[8192][512] bf16 h1, COMPACT bucket order
// total ~41.3 MB

__device__ __forceinline__ u16 f2bf(float f) {
  union { float f; unsigned u; } v; v.f = f;
  unsigned r = (v.u + 0x7fffu + ((v.u >> 16) & 1u)) >> 16;  // RNE
  return (u16)r;
}

struct __align__(8) U16x4 { u16 x, y, z, w; };

// Async global->LDS DMA, 16B/lane; LDS dest = wave-uniform base + lane*16,
// global SOURCE is per-lane (enables source-side swizzle).
__device__ __forceinline__ void dma16(const u16* gp, u16* lp) {
  __builtin_amdgcn_global_load_lds(
      (const __attribute__((address_space(1))) void*)gp,
      (__attribute__((address_space(3))) void*)lp, 16, 0, 0);
}

#define W1_TILES (KC * (DIN / 32) * (DH / 32))  // 5120
#define W2_TILES (KC * (DH / 32) * (DH / 32))   // 2560
#define NMB 256   // mega grid == CU count -> co-residency guaranteed

__device__ __forceinline__ void gbar(int* bar, int target) {
  __syncthreads();
  if (threadIdx.x == 0) {
    __threadfence();
    __hip_atomic_fetch_add(bar, 1, __ATOMIC_RELEASE, __HIP_MEMORY_SCOPE_AGENT);
    while (__hip_atomic_load(bar, __ATOMIC_ACQUIRE,
                             __HIP_MEMORY_SCOPE_AGENT) < target) {
      __builtin_amdgcn_s_sleep(1);
    }
  }
  __syncthreads();
}

// ---------------------------------------------------------------------------
// Mega kernel: P0 bucket + psum-zero + W-pack | bar | P1 compact x-pack |
// bar | P2 phi1 (128x128 units) | bar | P3 phi2. 256 blocks x 512 threads.
__global__ __launch_bounds__(512, 2) void mega_kernel(
    const int* __restrict__ cid, int* __restrict__ cnt,
    int* __restrict__ idxlist, const float* __restrict__ W1,
    const float* __restrict__ W2, u16* __restrict__ W1p,
    u16* __restrict__ W2p, const float* __restrict__ x,
    u16* __restrict__ xc, const float* __restrict__ b1,
    const float* __restrict__ b2, u16* __restrict__ h1,
    float* __restrict__ psum, int* __restrict__ bar) {
  __shared__ __align__(16) u16 lds[17408];     // 34.8 KB: stage bufs / epilogue
  __shared__ u16 wtile[2][32][33];             // 4.2 KB: W-pack transpose
  __shared__ int lcnt[KC], lbase[KC];

  const int b = blockIdx.x, tid = threadIdx.x;
  const int w = tid >> 6, lane = tid & 63;
  const int quad = lane >> 4, l16 = lane & 15;
  const int wr = w & 3, wc = w >> 2;           // 4 row-strips x 2 col-strips
  const int rl = lane >> 2, gl = lane & 3;
  const int gsw = gl ^ ((rl >> 1) & 3);        // A-source granule swizzle
  const int rsw = (quad ^ ((l16 >> 1) & 3)) << 3;  // frag-read granule

  // ---- P0a: bucket (blocks 0..31; 256 patches each)
  if (b < 32) {
    if (tid < KC) lcnt[tid] = 0;
    __syncthreads();
    int myk = 0, myoff = 0;
    if (tid < 256) {
      myk = cid[b * 256 + tid];
      myoff = atomicAdd(&lcnt[myk], 1);
    }
    __syncthreads();
    if (tid < KC) lbase[tid] = atomicAdd(&cnt[tid], lcnt[tid]);
    __syncthreads();
    if (tid < 256) idxlist[myk * NPATCH + lbase[myk] + myoff] = b * 256 + tid;
  }
  // ---- P0b: psum zero (block 32)
  if (b == 32) {
    for (int e = tid; e < KC * DH; e += 512) psum[e] = 0.f;
  }
  // ---- P0c: W-pack (all blocks; 2 tiles/iter x 15 iters = 7680 tiles)
  {
    const int sub = tid >> 8, tt = tid & 255;
    for (int i = 0; i < 15; ++i) {
      int bb = i * 512 + b * 2 + sub;
      const float* src;
      u16* dst;
      if (bb < W1_TILES) {
        int k = bb / 512, rem = bb % 512;
        int kb = rem / 16, n0 = (rem % 16) * 32;
        src = W1 + (size_t)k * DIN * DH + (size_t)kb * 32 * DH + n0;
        dst = W1p + (((size_t)(k * 32 + kb) * 512 + n0) * 32);
      } else {
        int b2_ = bb - W1_TILES;
        int k = b2_ / 256, rem = b2_ % 256;
        int kb = rem / 16, n0 = (rem % 16) * 32;
        src = W2 + (size_t)k * DH * DH + (size_t)kb * 32 * DH + n0;
        dst = W2p + (((size_t)(k * 16 + kb) * 512 + n0) * 32);
      }
      {
        int ki = tt >> 3, n4 = (tt & 7) * 4;
        float4 v = *(const float4*)&src[(size_t)ki * DH + n4];
        wtile[sub][ki][n4 + 0] = f2bf(v.x);
        wtile[sub][ki][n4 + 1] = f2bf(v.y);
        wtile[sub][ki][n4 + 2] = f2bf(v.z);
        wtile[sub][ki][n4 + 3] = f2bf(v.w);
      }
      __syncthreads();
      {
        int n = tt >> 3, ki = (tt & 7) * 4;
        U16x4 o = {wtile[sub][ki + 0][n], wtile[sub][ki + 1][n],
                   wtile[sub][ki + 2][n], wtile[sub][ki + 3][n]};
        int kis = ki ^ (((n >> 1) & 3) << 3);   // granule XOR swizzle
        *(U16x4*)&dst[(size_t)n * 32 + kis] = o;
      }
      __syncthreads();
    }
  }
  gbar(&bar[0], NMB);

  int cn[KC];
#pragma unroll
  for (int i = 0; i < KC; ++i) cn[i] = cnt[i];

  // ---- P1: compact x-pack (block b: compact rows b*32..+31)
  {
    int rowc = b * 32 + (tid >> 4);
    int kk = 0, accp = 0;
#pragma unroll
    for (int i = 0; i < KC - 1; ++i) {
      accp += cn[i];
      if (rowc >= accp) kk = i + 1;
    }
    int cbase = 0;
#pragma unroll
    for (int i = 0; i < KC - 1; ++i) cbase += (i < kk) ? cn[i] : 0;
    int src = idxlist[kk * NPATCH + rowc - cbase];
    const float4* xp = (const float4*)(x + (size_t)src * DIN + (tid & 15) * 64);
    U16x4* dst = (U16x4*)(xc + (size_t)rowc * DIN + (tid & 15) * 64);
#pragma unroll
    for (int j = 0; j < 16; ++j) {
      float4 v = xp[j];
      U16x4 o = {f2bf(v.x), f2bf(v.y), f2bf(v.z), f2bf(v.w)};
      dst[j] = o;
    }
  }
  gbar(&bar[1], NMB);

  int nch[KC], NU = 0;
#pragma unroll
  for (int i = 0; i < KC; ++i) {
    nch[i] = (cn[i] + 127) >> 7;
    NU += nch[i];
  }

  u16* As = lds;          // 2 x 4096 u16 (8KB/buf)
  u16* Bs = lds + 8192;   // 2 x 4096 u16

  const f32x4 zero4 = {0.f, 0.f, 0.f, 0.f};

  // ---- P2: phi1 — units of 128 rows x 128 cols, K=1024 (32 steps)
  for (int u = b; u < 4 * NU; u += NMB) {
    const int slice = u & 3;
    int c = u >> 2, kk = 0;
#pragma unroll
    for (int i = 0; i < KC - 1; ++i) {
      if (c >= nch[i]) { c -= nch[i]; kk = i + 1; }
    }
    int cbase = 0;
#pragma unroll
    for (int i = 0; i < KC - 1; ++i) cbase += (i < kk) ? cn[i] : 0;
    const int cntk = cn[kk];
    const int base = c * 128;

    __syncthreads();   // lds reuse across units

    int grow = cbase + base + w * 16 + rl;
    if (grow > NPATCH - 1) grow = NPATCH - 1;
    const u16* asrc = xc + (size_t)grow * DIN + gsw * 8;
    const u16* bsrc =
        W1p + ((size_t)(kk * 32) * 512 + slice * 128 + w * 16 + rl) * 32 +
        gl * 8;

    dma16(asrc, As + w * 512);
    dma16(bsrc, Bs + w * 512);

    f32x4 acc[2][4];
#pragma unroll
    for (int fr = 0; fr < 2; ++fr)
#pragma unroll
      for (int fc = 0; fc < 4; ++fc) acc[fr][fc] = zero4;

    for (int t = 0; t < 32; ++t) {
      const int buf = t & 1;
      if (t < 31) {
        const int bn = buf ^ 1;
        dma16(asrc + (t + 1) * 32, As + bn * 4096 + w * 512);
        dma16(bsrc + (size_t)(t + 1) * 16384, Bs + bn * 4096 + w * 512);
        asm volatile("s_waitcnt vmcnt(2)" ::: "memory");
      } else {
        asm volatile("s_waitcnt vmcnt(0)" ::: "memory");
      }
      __syncthreads();
      bf16x8 af[2], bfr[4];
#pragma unroll
      for (int fr = 0; fr < 2; ++fr) {
        int row = wr * 32 + fr * 16 + l16;
        af[fr] = *(const bf16x8*)&As[buf * 4096 + row * 32 + rsw];
      }
#pragma unroll
      for (int fc = 0; fc < 4; ++fc) {
        int col = wc * 64 + fc * 16 + l16;
        bfr[fc] = *(const bf16x8*)&Bs[buf * 4096 + col * 32 + rsw];
      }
#pragma unroll
      for (int fr = 0; fr < 2; ++fr)
#pragma unroll
        for (int fc = 0; fc < 4; ++fc)
          acc[fr][fc] = __builtin_amdgcn_mfma_f32_16x16x32_bf16(
              af[fr], bfr[fc], acc[fr][fc], 0, 0, 0);
      __syncthreads();
    }

    // epilogue: bias+relu -> bf16 via lds[128*136] -> compact h1
#pragma unroll
    for (int fr = 0; fr < 2; ++fr)
#pragma unroll
      for (int fc = 0; fc < 4; ++fc) {
        int col = wc * 64 + fc * 16 + l16;
        float bias = b1[kk * DH + slice * 128 + col];
#pragma unroll
        for (int r = 0; r < 4; ++r) {
          int row = wr * 32 + fr * 16 + quad * 4 + r;
          lds[row * 136 + col] = f2bf(fmaxf(acc[fr][fc][r] + bias, 0.f));
        }
      }
    __syncthreads();
    {
      int row = tid >> 2, seg = tid & 3;
      if (base + row < cntk) {
        u16* dst = h1 + (size_t)(cbase + base + row) * DH + slice * 128 +
                   seg * 32;
#pragma unroll
        for (int j = 0; j < 4; ++j)
          *(bf16x8*)(dst + j * 8) =
              *(const bf16x8*)&lds[row * 136 + seg * 32 + j * 8];
      }
    }
  }
  gbar(&bar[2], NMB);

  // ---- P3: phi2 — units of 128x128, K=512 (16 steps), masked psum epilogue
  for (int u = b; u < 4 * NU; u += NMB) {
    const int slice = u & 3;
    int c = u >> 2, kk = 0;
#pragma unroll
    for (int i = 0; i < KC - 1; ++i) {
      if (c >= nch[i]) { c -= nch[i]; kk = i + 1; }
    }
    int cbase = 0;
#pragma unroll
    for (int i = 0; i < KC - 1; ++i) cbase += (i < kk) ? cn[i] : 0;
    const int cntk = cn[kk];
    const int base = c * 128;

    __syncthreads();

    int grow = cbase + base + w * 16 + rl;
    if (grow > NPATCH - 1) grow = NPATCH - 1;
    const u16* asrc = h1 + (size_t)grow * DH + gsw * 8;
    const u16* bsrc =
        W2p + ((size_t)(kk * 16) * 512 + slice * 128 + w * 16 + rl) * 32 +
        gl * 8;

    dma16(asrc, As + w * 512);
    dma16(bsrc, Bs + w * 512);

    f32x4 acc[2][4];
#pragma unroll
    for (int fr = 0; fr < 2; ++fr)
#pragma unroll
      for (int fc = 0; fc < 4; ++fc) acc[fr][fc] = zero4;

    for (int t = 0; t < 16; ++t) {
      const int buf = t & 1;
      if (t < 15) {
        const int bn = buf ^ 1;
        dma16(asrc + (t + 1) * 32, As + bn * 4096 + w * 512);
        dma16(bsrc + (size_t)(t + 1) * 16384, Bs + bn * 4096 + w * 512);
        asm volatile("s_waitcnt vmcnt(2)" ::: "memory");
      } else {
        asm volatile("s_waitcnt vmcnt(0)" ::: "memory");
      }
      __syncthreads();
      bf16x8 af[2], bfr[4];
#pragma unroll
      for (int fr = 0; fr < 2; ++fr) {
        int row = wr * 32 + fr * 16 + l16;
        af[fr] = *(const bf16x8*)&As[buf * 4096 + row * 32 + rsw];
      }
#pragma unroll
      for (int fc = 0; fc < 4; ++fc) {
        int col = wc * 64 + fc * 16 + l16;
        bfr[fc] = *(const bf16x8*)&Bs[buf * 4096 + col * 32 + rsw];
      }
#pragma unroll
      for (int fr = 0; fr < 2; ++fr)
#pragma unroll
        for (int fc = 0; fc < 4; ++fc)
          acc[fr][fc] = __builtin_amdgcn_mfma_f32_16x16x32_bf16(
              af[fr], bfr[fc], acc[fr][fc], 0, 0, 0);
      __syncthreads();
    }

    // masked mean-pool numerator -> psum atomics
#pragma unroll
    for (int fc = 0; fc < 4; ++fc) {
      int col = wc * 64 + fc * 16 + l16;
      float bias = b2[kk * DH + slice * 128 + col];
      float sv = 0.f;
#pragma unroll
      for (int fr = 0; fr < 2; ++fr)
#pragma unroll
        for (int r = 0; r < 4; ++r) {
          int row = base + wr * 32 + fr * 16 + quad * 4 + r;
          sv += (row < cntk) ? fmaxf(acc[fr][fc][r] + bias, 0.f) : 0.f;
        }
      sv += __shfl_xor(sv, 16, 64);
      sv += __shfl_xor(sv, 32, 64);
      if (quad == 0) atomicAdd(&psum[kk * DH + slice * 128 + col], sv);
    }
  }
}

// ---------------------------------------------------------------------------
// Fused tail: fc + gated-attn + softmax + rho + classifier in ONE kernel.
// 64 blocks x 256 threads, device-scope spin barriers (slots bar[0..2] of
// the pointer passed in = global bar[3..5]).
#define NTB 64

__device__ __forceinline__ void bar_arrive_wait(int* bar) {
  __syncthreads();
  if (threadIdx.x == 0) {
    __threadfence();
    __hip_atomic_fetch_add(bar, 1, __ATOMIC_RELEASE, __HIP_MEMORY_SCOPE_AGENT);
    while (__hip_atomic_load(bar, __ATOMIC_ACQUIRE,
                             __HIP_MEMORY_SCOPE_AGENT) < NTB) {
      __builtin_amdgcn_s_sleep(1);
    }
  }
  __syncthreads();
}

__global__ __launch_bounds__(256) void tail_kernel(
    const float* __restrict__ psum, const int* __restrict__ cnt,
    const float* __restrict__ fcW, const float* __restrict__ fcb,
    const float* __restrict__ Va, const float* __restrict__ ba,
    const float* __restrict__ Vb, const float* __restrict__ bb_,
    const float* __restrict__ Vc, const float* __restrict__ rhoW,
    const float* __restrict__ rhob, const float* __restrict__ clsW,
    const float* __restrict__ clsb, float* __restrict__ hstore,
    float* __restrict__ sred, float* __restrict__ h2g,
    int* __restrict__ bar, float* __restrict__ out) {
  __shared__ float p_sh[KC * DH];      // 20 KB (pooled feats, then hstore)
  __shared__ float r1[2560];           // 10 KB
  __shared__ float r2[2560];           // 10 KB
  __shared__ float invs[KC];
  __shared__ float gate_sh[4 * KC];
  __shared__ float ws_sh[KC];
  __shared__ float hp_sh[DH];
  const int tid = threadIdx.x;
  const int b = blockIdx.x;

  // ---- stage 1: fc — hstore[k][j] for j in [b*8, b*8+8)
  if (tid < KC) {
    int c = cnt[tid];
    invs[tid] = (c > 0) ? 1.f / (float)c : 0.f;
  }
  __syncthreads();
#pragma unroll
  for (int it = 0; it < KC * DH / 256; ++it) {
    int e = it * 256 + tid;
    p_sh[e] = psum[e] * invs[e >> 9];
  }
  __syncthreads();
  {
    const int jj = tid & 7, dq = tid >> 3;   // 8 j x 32 d-chunks of 16
    const int j0 = b * 8;
    float acc[KC];
#pragma unroll
    for (int k = 0; k < KC; ++k) acc[k] = 0.f;
#pragma unroll 4
    for (int i = 0; i < 16; ++i) {
      int d = dq * 16 + i;
      float wv = fcW[(size_t)d * DH + j0 + jj];
#pragma unroll
      for (int k = 0; k < KC; ++k) acc[k] = fmaf(p_sh[k * DH + d], wv, acc[k]);
    }
#pragma unroll
    for (int k = 0; k < KC; ++k) r1[(dq * 8 + jj) * KC + k] = acc[k];
    __syncthreads();
    if (tid < 8 * KC) {
      int jj2 = tid / KC, k = tid % KC;
      float s = 0.f;
#pragma unroll
      for (int q = 0; q < 32; ++q) s += r1[(q * 8 + jj2) * KC + k];
      hstore[k * DH + j0 + jj2] = fmaxf(s + fcb[j0 + jj2], 0.f);
    }
  }
  bar_arrive_wait(&bar[0]);

  // ---- stage 2: gated attention partials — 4 j per block
#pragma unroll
  for (int it = 0; it < KC * DH / 256; ++it) {
    int e = it * 256 + tid;
    p_sh[e] = hstore[e];
  }
  __syncthreads();
  {
    const int jj = tid & 3, dq = tid >> 2;   // 4 j x 64 d-chunks of 8
    const int j0 = b * 4;
    float sa[KC], sb[KC];
#pragma unroll
    for (int k = 0; k < KC; ++k) { sa[k] = 0.f; sb[k] = 0.f; }
#pragma unroll 4
    for (int i = 0; i < 8; ++i) {
      int d = dq * 8 + i;
      float va = Va[(size_t)d * DA + j0 + jj];
      float vb = Vb[(size_t)d * DA + j0 + jj];
#pragma unroll
      for (int k = 0; k < KC; ++k) {
        float h = p_sh[k * DH + d];
        sa[k] = fmaf(h, va, sa[k]);
        sb[k] = fmaf(h, vb, sb[k]);
      }
    }
#pragma unroll
    for (int k = 0; k < KC; ++k) {
      r1[(dq * 4 + jj) * KC + k] = sa[k];
      r2[(dq * 4 + jj) * KC + k] = sb[k];
    }
    __syncthreads();
    if (tid < 4 * KC) {
      int jj2 = tid / KC, k = tid % KC;
      float ta = 0.f, tb = 0.f;
#pragma unroll
      for (int q = 0; q < 64; ++q) {
        ta += r1[(q * 4 + jj2) * KC + k];
        tb += r2[(q * 4 + jj2) * KC + k];
      }
      float a = tanhf(ta + ba[j0 + jj2]);
      float g = 1.f / (1.f + expf(-(tb + bb_[j0 + jj2])));
      gate_sh[jj2 * KC + k] = a * g * Vc[j0 + jj2];  // bc dropped: shift-inv
    }
    __syncthreads();
    if (tid < KC) {
      float s = 0.f;
#pragma unroll
      for (int jj2 = 0; jj2 < 4; ++jj2) s += gate_sh[jj2 * KC + tid];
      sred[b * 16 + tid] = s;
    }
  }
  bar_arrive_wait(&bar[1]);

  // ---- stage 3: softmax over clusters + h_path + rho (4 j per block)
  if (tid < KC) {
    float s = 0.f;
    for (int q = 0; q < NTB; ++q) s += sred[q * 16 + tid];
    ws_sh[tid] = s;
  }
  __syncthreads();
  if (tid == 0) {
    float m = -1e30f;
#pragma unroll
    for (int k2 = 0; k2 < KC; ++k2) m = fmaxf(m, ws_sh[k2]);
    float Z = 0.f;
#pragma unroll
    for (int k2 = 0; k2 < KC; ++k2) {
      float e = expf(ws_sh[k2] - m);
      ws_sh[k2] = e;
      Z += e;
    }
    float iZ = 1.f / Z;
#pragma unroll
    for (int k2 = 0; k2 < KC; ++k2) ws_sh[k2] *= iZ;
  }
  __syncthreads();
#pragma unroll
  for (int it = 0; it < 2; ++it) {
    int d = it * 256 + tid;
    float s = 0.f;
#pragma unroll
    for (int k2 = 0; k2 < KC; ++k2) s = fmaf(ws_sh[k2], p_sh[k2 * DH + d], s);
    hp_sh[d] = s;
  }
  __syncthreads();
  {
    const int jj = tid & 3, dq = tid >> 2;
    const int j0 = b * 4;
    float acc = 0.f;
#pragma unroll 4
    for (int i = 0; i < 8; ++i) {
      int d = dq * 8 + i;
      acc = fmaf(hp_sh[d], rhoW[(size_t)d * DA + j0 + jj], acc);
    }
    r1[dq * 4 + jj] = acc;
    __syncthreads();
    if (tid < 4) {
      float s = 0.f;
#pragma unroll
      for (int q = 0; q < 64; ++q) s += r1[q * 4 + tid];
      h2g[j0 + tid] = fmaxf(s + rhob[j0 + tid], 0.f);
    }
  }

  // ---- stage 4: classifier (block 0 only; others arrive and exit)
  if (b != 0) {
    __syncthreads();
    if (tid == 0) {
      __threadfence();
      __hip_atomic_fetch_add(&bar[2], 1, __ATOMIC_RELEASE,
                             __HIP_MEMORY_SCOPE_AGENT);
    }
    return;
  }
  bar_arrive_wait(&bar[2]);
  {
    float h = h2g[tid];
#pragma unroll
    for (int c = 0; c < NCLS; ++c)
      r1[c * 256 + tid] = h * clsW[(size_t)tid * NCLS + c];
    __syncthreads();
    for (int s = 128; s > 0; s >>= 1) {
      if (tid < s) {
#pragma unroll
        for (int c = 0; c < NCLS; ++c)
          r1[c * 256 + tid] += r1[c * 256 + tid + s];
      }
      __syncthreads();
    }
    if (tid == 0) {
      float lg[NCLS], hz[NCLS];
      int best = 0;
#pragma unroll
      for (int c = 0; c < NCLS; ++c) {
        lg[c] = r1[c * 256] + clsb[c];
        hz[c] = 1.f / (1.f + expf(-lg[c]));
        if (lg[c] > lg[best]) best = c;
      }
      float S = 1.f;
#pragma unroll
      for (int c = 0; c < NCLS; ++c) out[c] = hz[c];
#pragma unroll
      for (int c = 0; c < NCLS; ++c) {
        S *= (1.f - hz[c]);
        out[NCLS + c] = S;
      }
      out[2 * NCLS] = (float)best;
    }
  }
}

extern "C" void kernel_launch(void* const* d_in, const int* in_sizes, int n_in,
                              void* d_out, int out_size, void* d_ws,
                              size_t ws_size, hipStream_t stream) {
  const float* x    = (const float*)d_in[0];
  const int*   cid  = (const int*)d_in[1];
  const float* W1   = (const float*)d_in[2];
  const float* b1   = (const float*)d_in[3];
  const float* W2   = (const float*)d_in[4];
  const float* b2   = (const float*)d_in[5];
  const float* fcW  = (const float*)d_in[6];
  const float* fcb  = (const float*)d_in[7];
  const float* Va   = (const float*)d_in[8];
  const float* ba   = (const float*)d_in[9];
  const float* Vb   = (const float*)d_in[10];
  const float* bb_  = (const float*)d_in[11];
  const float* Vc   = (const float*)d_in[12];
  const float* rhoW = (const float*)d_in[14];
  const float* rhob = (const float*)d_in[15];
  const float* clsW = (const float*)d_in[16];
  const float* clsb = (const float*)d_in[17];
  float* out = (float*)d_out;

  char* ws = (char*)d_ws;
  int*   cnt     = (int*)(ws + OFF_CNT);
  int*   bar     = (int*)(ws + OFF_BAR);
  int*   idxlist = (int*)(ws + OFF_IDX);
  float* psum    = (float*)(ws + OFF_PSUM);
  float* hstore  = (float*)(ws + OFF_H);
  float* h2g     = (float*)(ws + OFF_H2);
  float* sred    = (float*)(ws + OFF_SRED);
  u16*   W1p     = (u16*)(ws + OFF_W1P);
  u16*   W2p     = (u16*)(ws + OFF_W2P);
  u16*   xc      = (u16*)(ws + OFF_XC);
  u16*   h1      = (u16*)(ws + OFF_H1);

  (void)hipMemsetAsync(cnt, 0, 128, stream);  // cnt[10] + bar[8]
  mega_kernel<<<NMB, 512, 0, stream>>>(cid, cnt, idxlist, W1, W2, W1p, W2p, x,
                                       xc, b1, b2, h1, psum, bar);
  tail_kernel<<<NTB, 256, 0, stream>>>(psum, cnt, fcW, fcb, Va, ba, Vb, bb_,
                                       Vc, rhoW, rhob, clsW, clsb, hstore,
                                       sred, h2g, bar + 3, out);
}

// Round 10
// 201.257 us; speedup vs baseline: 2.0891x; 2.0891x over previous
//
#include <hip/hip_runtime.h>
#include <math.h>

// Problem constants (from reference)
#define NPATCH 8192
#define KC     10
#define DIN    1024
#define DH     512
#define DA     256
#define NCLS   4

#define TM  32    // patches per phi tile
#define LDA 520   // padded LDS row stride (u16)

typedef unsigned short u16;
typedef short bf16x8 __attribute__((ext_vector_type(8)));   // 8 bf16 = 4 VGPRs
typedef float f32x4  __attribute__((ext_vector_type(4)));

// Workspace layout (bytes)
#define OFF_CNT   0                  // int[KC] (40B)
#define OFF_BAR   48                 // int[3] spin-barrier counters (covered by 64B memset)
#define OFF_IDX   64                 // int[KC*NPATCH]
#define OFF_PSUM  327744             // float[KC*DH]
#define OFF_H     348224             // float[KC*DH]
#define OFF_H2    368768             // float[DA] (1KB)
#define OFF_SRED  369792             // float[64*16] per-block attn partials
#define OFF_W1P   373888             // u16[KC*DIN*DH]
#define OFF_W2P   10859648           // u16[KC*DH*DH]
// total ~16 MB

__device__ __forceinline__ u16 f2bf(float f) {
  union { float f; unsigned u; } v; v.f = f;
  unsigned r = (v.u + 0x7fffu + ((v.u >> 16) & 1u)) >> 16;  // RNE
  return (u16)r;
}

// packed RNE f32x2 -> bf16x2 (low = lo)
__device__ __forceinline__ unsigned cvtpk(float lo, float hi) {
  unsigned r;
  asm("v_cvt_pk_bf16_f32 %0, %1, %2" : "=v"(r) : "v"(lo), "v"(hi));
  return r;
}

struct __align__(8) U16x4 { u16 x, y, z, w; };
union BF8U { bf16x8 v; unsigned u[4]; };

#define W1_TILES (KC * (DIN / 32) * (DH / 32))  // 5120
#define W2_TILES (KC * (DH / 32) * (DH / 32))   // 2560
#define NB_BUCKET 32
#define NB_PREP (NB_BUCKET + W1_TILES + W2_TILES)  // 7712

// Fused prep: bucket + zero psum (blocks 0..31), pack W1/W2 -> bf16
// MFMA-B panels [k][kb][n][ki].
__global__ __launch_bounds__(256) void prep_kernel(
    const int* __restrict__ cid, int* __restrict__ cnt,
    int* __restrict__ idxlist, const float* __restrict__ W1,
    const float* __restrict__ W2, u16* __restrict__ W1p,
    u16* __restrict__ W2p, float* __restrict__ psum) {
  int b = blockIdx.x, t = threadIdx.x;
  if (b < NB_BUCKET) {
    int g = b * 256 + t;
    if (g < KC * DH) psum[g] = 0.f;
    __shared__ int lcnt[KC], lbase[KC];
    if (t < KC) lcnt[t] = 0;
    __syncthreads();
    int n = b * 256 + t;                 // NPATCH == 32*256
    int k = cid[n];
    int myoff = atomicAdd(&lcnt[k], 1);
    __syncthreads();
    if (t < KC) lbase[t] = atomicAdd(&cnt[t], lcnt[t]);
    __syncthreads();
    idxlist[k * NPATCH + lbase[k] + myoff] = n;
  } else {
    __shared__ u16 tile[32][33];
    int bb = b - NB_BUCKET;
    const float* src;
    u16* dst;
    if (bb < W1_TILES) {
      int k = bb / 512, rem = bb % 512;
      int kb = rem / 16, n0 = (rem % 16) * 32;
      src = W1 + (size_t)k * DIN * DH + (size_t)kb * 32 * DH + n0;
      dst = W1p + (((size_t)(k * 32 + kb) * 512 + n0) * 32);
    } else {
      int b2 = bb - W1_TILES;
      int k = b2 / 256, rem = b2 % 256;
      int kb = rem / 16, n0 = (rem % 16) * 32;
      src = W2 + (size_t)k * DH * DH + (size_t)kb * 32 * DH + n0;
      dst = W2p + (((size_t)(k * 16 + kb) * 512 + n0) * 32);
    }
    {
      int ki = t >> 3, n4 = (t & 7) * 4;
      float4 v = *(const float4*)&src[(size_t)ki * DH + n4];
      tile[ki][n4 + 0] = f2bf(v.x);
      tile[ki][n4 + 1] = f2bf(v.y);
      tile[ki][n4 + 2] = f2bf(v.z);
      tile[ki][n4 + 3] = f2bf(v.w);
    }
    __syncthreads();
    {
      int n = t >> 3, ki = (t & 7) * 4;
      U16x4 o = {tile[ki + 0][n], tile[ki + 1][n], tile[ki + 2][n],
                 tile[ki + 3][n]};
      *(U16x4*)&dst[(size_t)n * 32 + ki] = o;
    }
  }
}

// Fused phi: per 32-patch tile, layer1 (K=1024) -> relu/bf16 H in LDS ->
// layer2 (K=512) -> masked rowsum -> psum atomics. No h1 global round-trip.
// 512 thr (8 waves, wave owns 64 cols, acc 2m x 4nt). Dynamic tile grab:
// XCD s=bid&7 takes contiguous tile range [G*s/8, G*(s+1)/8) -> same-cluster
// tiles colocated (panels L2-resident) + balanced XCD load.
__global__ __launch_bounds__(512, 4) void phi_kernel(
    const float* __restrict__ x, const u16* __restrict__ W1p,
    const u16* __restrict__ W2p, const float* __restrict__ b1,
    const float* __restrict__ b2, const int* __restrict__ cnt,
    const int* __restrict__ idxlist, float* __restrict__ psum) {
  __shared__ __align__(16) u16 A0[TM * LDA];   // 33.3 KB (x kh0, then H)
  __shared__ __align__(16) u16 A1[TM * LDA];   // 33.3 KB (x kh1)
  __shared__ int ridx[TM];

  const int tid = threadIdx.x;
  const int w = tid >> 6, lane = tid & 63;
  const int quad = lane >> 4, l16 = lane & 15;

  int cn[KC];
#pragma unroll
  for (int i = 0; i < KC; ++i) cn[i] = cnt[i];
  int G = 0;
#pragma unroll
  for (int i = 0; i < KC; ++i) G += (cn[i] + TM - 1) >> 5;

  const int s = blockIdx.x & 7, j = blockIdx.x >> 3;
  const int lo = (G * s) >> 3, hi = (G * (s + 1)) >> 3;

  for (int g = lo + j; g < hi; g += 64) {
    // locate (cluster kk, chunk rg) for global tile g — all-static indexing
    int kk = 0, rg = g, cntk = cn[0];
#pragma unroll
    for (int i = 0; i < KC - 1; ++i) {
      int nch = (cn[i] + TM - 1) >> 5;
      if (rg >= nch) { kk = i + 1; rg -= nch; cntk = cn[i + 1]; }
    }
    const int base = rg * TM;

    if (tid < TM)
      ridx[tid] = (base + tid < cntk) ? idxlist[kk * NPATCH + base + tid] : -1;
    __syncthreads();   // also guards LDS reuse across tile iterations

    // ---- stage x tile: 32 rows x 1024 cols bf16 into A0 (kh0) + A1 (kh1)
#pragma unroll
    for (int u8 = 0; u8 < 8; ++u8) {
      const int kh = u8 & 1;
      const int r = w * 4 + (u8 >> 1);
      int src = ridx[r];
      BF8U o;
      if (src >= 0) {
        const float4* xp =
            (const float4*)(x + (size_t)src * DIN + kh * 512 + lane * 8);
        float4 v0 = xp[0], v1 = xp[1];
        o.u[0] = cvtpk(v0.x, v0.y);
        o.u[1] = cvtpk(v0.z, v0.w);
        o.u[2] = cvtpk(v1.x, v1.y);
        o.u[3] = cvtpk(v1.z, v1.w);
      } else {
        o.u[0] = 0; o.u[1] = 0; o.u[2] = 0; o.u[3] = 0;
      }
      u16* dstbuf = kh ? A1 : A0;
      *(bf16x8*)&dstbuf[r * LDA + lane * 8] = o.v;
    }
    __syncthreads();

    // ---- layer1: acc[2][4] over K=1024 (two 512-halves from A0/A1)
    const f32x4 zero4 = {0.f, 0.f, 0.f, 0.f};
    f32x4 acc[2][4];
#pragma unroll
    for (int m = 0; m < 2; ++m)
#pragma unroll
      for (int nt = 0; nt < 4; ++nt) acc[m][nt] = zero4;

#pragma unroll
    for (int kh = 0; kh < 2; ++kh) {
      const u16* Abuf = kh ? A1 : A0;
      const u16* wb = W1p + ((size_t)(kk * 32 + kh * 16) * 512 +
                             (w * 64 + l16)) * 32 + quad * 8;
      bf16x8 B[2][4];
#pragma unroll
      for (int nt = 0; nt < 4; ++nt)
        B[0][nt] = *(const bf16x8*)(wb + nt * 512);
#pragma unroll
      for (int ks = 0; ks < 16; ++ks) {
        const int cur = ks & 1, nxt = cur ^ 1;
        if (ks < 15) {
#pragma unroll
          for (int nt = 0; nt < 4; ++nt)
            B[nxt][nt] =
                *(const bf16x8*)(wb + (size_t)(ks + 1) * 16384 + nt * 512);
        }
        bf16x8 af0 = *(const bf16x8*)&Abuf[l16 * LDA + ks * 32 + quad * 8];
        bf16x8 af1 =
            *(const bf16x8*)&Abuf[(16 + l16) * LDA + ks * 32 + quad * 8];
#pragma unroll
        for (int nt = 0; nt < 4; ++nt) {
          acc[0][nt] = __builtin_amdgcn_mfma_f32_16x16x32_bf16(
              af0, B[cur][nt], acc[0][nt], 0, 0, 0);
          acc[1][nt] = __builtin_amdgcn_mfma_f32_16x16x32_bf16(
              af1, B[cur][nt], acc[1][nt], 0, 0, 0);
        }
      }
    }
    __syncthreads();   // all waves done reading A0/A1

    // ---- H = relu(acc + b1) -> bf16 into A0
#pragma unroll
    for (int m = 0; m < 2; ++m)
#pragma unroll
      for (int nt = 0; nt < 4; ++nt) {
        int c = w * 64 + nt * 16 + l16;
        float bias = b1[kk * DH + c];
#pragma unroll
        for (int r = 0; r < 4; ++r) {
          int row = m * 16 + quad * 4 + r;
          A0[row * LDA + c] = f2bf(fmaxf(acc[m][nt][r] + bias, 0.f));
        }
      }
    __syncthreads();

    // ---- layer2: acc2[2][4] over K=512 from H (A0)
    f32x4 acc2[2][4];
#pragma unroll
    for (int m = 0; m < 2; ++m)
#pragma unroll
      for (int nt = 0; nt < 4; ++nt) acc2[m][nt] = zero4;

    {
      const u16* wb2 = W2p + ((size_t)(kk * 16) * 512 +
                              (w * 64 + l16)) * 32 + quad * 8;
      bf16x8 B[2][4];
#pragma unroll
      for (int nt = 0; nt < 4; ++nt)
        B[0][nt] = *(const bf16x8*)(wb2 + nt * 512);
#pragma unroll
      for (int ks = 0; ks < 16; ++ks) {
        const int cur = ks & 1, nxt = cur ^ 1;
        if (ks < 15) {
#pragma unroll
          for (int nt = 0; nt < 4; ++nt)
            B[nxt][nt] =
                *(const bf16x8*)(wb2 + (size_t)(ks + 1) * 16384 + nt * 512);
        }
        bf16x8 af0 = *(const bf16x8*)&A0[l16 * LDA + ks * 32 + quad * 8];
        bf16x8 af1 =
            *(const bf16x8*)&A0[(16 + l16) * LDA + ks * 32 + quad * 8];
#pragma unroll
        for (int nt = 0; nt < 4; ++nt) {
          acc2[0][nt] = __builtin_amdgcn_mfma_f32_16x16x32_bf16(
              af0, B[cur][nt], acc2[0][nt], 0, 0, 0);
          acc2[1][nt] = __builtin_amdgcn_mfma_f32_16x16x32_bf16(
              af1, B[cur][nt], acc2[1][nt], 0, 0, 0);
        }
      }
    }

    // ---- masked mean-pool numerator -> psum atomics
    float vmask[2][4];
#pragma unroll
    for (int m = 0; m < 2; ++m)
#pragma unroll
      for (int r = 0; r < 4; ++r)
        vmask[m][r] = (base + m * 16 + quad * 4 + r < cntk) ? 1.f : 0.f;

#pragma unroll
    for (int nt = 0; nt < 4; ++nt) {
      int col = w * 64 + nt * 16 + l16;
      float bias = b2[kk * DH + col];
      float sv = 0.f;
#pragma unroll
      for (int m = 0; m < 2; ++m)
#pragma unroll
        for (int r = 0; r < 4; ++r)
          sv += vmask[m][r] * fmaxf(acc2[m][nt][r] + bias, 0.f);
      sv += __shfl_xor(sv, 16, 64);
      sv += __shfl_xor(sv, 32, 64);
      if (quad == 0) atomicAdd(&psum[kk * DH + col], sv);
    }
  }
}

// ---------------------------------------------------------------------------
// Fused tail: fc + gated-attn + softmax + rho + classifier in ONE kernel.
// 64 blocks x 256 threads, device-scope spin barriers between stages.
#define NTB 64

__device__ __forceinline__ void bar_arrive_wait(int* bar) {
  __syncthreads();
  if (threadIdx.x == 0) {
    __threadfence();
    __hip_atomic_fetch_add(bar, 1, __ATOMIC_RELEASE, __HIP_MEMORY_SCOPE_AGENT);
    while (__hip_atomic_load(bar, __ATOMIC_ACQUIRE,
                             __HIP_MEMORY_SCOPE_AGENT) < NTB) {
      __builtin_amdgcn_s_sleep(1);
    }
  }
  __syncthreads();
}

__global__ __launch_bounds__(256) void tail_kernel(
    const float* __restrict__ psum, const int* __restrict__ cnt,
    const float* __restrict__ fcW, const float* __restrict__ fcb,
    const float* __restrict__ Va, const float* __restrict__ ba,
    const float* __restrict__ Vb, const float* __restrict__ bb_,
    const float* __restrict__ Vc, const float* __restrict__ rhoW,
    const float* __restrict__ rhob, const float* __restrict__ clsW,
    const float* __restrict__ clsb, float* __restrict__ hstore,
    float* __restrict__ sred, float* __restrict__ h2g,
    int* __restrict__ bar, float* __restrict__ out) {
  __shared__ float p_sh[KC * DH];      // 20 KB (pooled feats, then hstore)
  __shared__ float r1[2560];           // 10 KB
  __shared__ float r2[2560];           // 10 KB
  __shared__ float invs[KC];
  __shared__ float gate_sh[4 * KC];
  __shared__ float ws_sh[KC];
  __shared__ float hp_sh[DH];
  const int tid = threadIdx.x;
  const int b = blockIdx.x;

  // ---- stage 1: fc — hstore[k][j] for j in [b*8, b*8+8)
  if (tid < KC) {
    int c = cnt[tid];
    invs[tid] = (c > 0) ? 1.f / (float)c : 0.f;
  }
  __syncthreads();
#pragma unroll
  for (int it = 0; it < KC * DH / 256; ++it) {
    int e = it * 256 + tid;
    p_sh[e] = psum[e] * invs[e >> 9];
  }
  __syncthreads();
  {
    const int jj = tid & 7, dq = tid >> 3;   // 8 j x 32 d-chunks of 16
    const int j0 = b * 8;
    float acc[KC];
#pragma unroll
    for (int k = 0; k < KC; ++k) acc[k] = 0.f;
#pragma unroll 4
    for (int i = 0; i < 16; ++i) {
      int d = dq * 16 + i;
      float wv = fcW[(size_t)d * DH + j0 + jj];
#pragma unroll
      for (int k = 0; k < KC; ++k) acc[k] = fmaf(p_sh[k * DH + d], wv, acc[k]);
    }
#pragma unroll
    for (int k = 0; k < KC; ++k) r1[(dq * 8 + jj) * KC + k] = acc[k];
    __syncthreads();
    if (tid < 8 * KC) {
      int jj2 = tid / KC, k = tid % KC;
      float s = 0.f;
#pragma unroll
      for (int q = 0; q < 32; ++q) s += r1[(q * 8 + jj2) * KC + k];
      hstore[k * DH + j0 + jj2] = fmaxf(s + fcb[j0 + jj2], 0.f);
    }
  }
  bar_arrive_wait(&bar[0]);

  // ---- stage 2: gated attention partials — 4 j per block
#pragma unroll
  for (int it = 0; it < KC * DH / 256; ++it) {
    int e = it * 256 + tid;
    p_sh[e] = hstore[e];
  }
  __syncthreads();
  {
    const int jj = tid & 3, dq = tid >> 2;   // 4 j x 64 d-chunks of 8
    const int j0 = b * 4;
    float sa[KC], sb[KC];
#pragma unroll
    for (int k = 0; k < KC; ++k) { sa[k] = 0.f; sb[k] = 0.f; }
#pragma unroll 4
    for (int i = 0; i < 8; ++i) {
      int d = dq * 8 + i;
      float va = Va[(size_t)d * DA + j0 + jj];
      float vb = Vb[(size_t)d * DA + j0 + jj];
#pragma unroll
      for (int k = 0; k < KC; ++k) {
        float h = p_sh[k * DH + d];
        sa[k] = fmaf(h, va, sa[k]);
        sb[k] = fmaf(h, vb, sb[k]);
      }
    }
#pragma unroll
    for (int k = 0; k < KC; ++k) {
      r1[(dq * 4 + jj) * KC + k] = sa[k];
      r2[(dq * 4 + jj) * KC + k] = sb[k];
    }
    __syncthreads();
    if (tid < 4 * KC) {
      int jj2 = tid / KC, k = tid % KC;
      float ta = 0.f, tb = 0.f;
#pragma unroll
      for (int q = 0; q < 64; ++q) {
        ta += r1[(q * 4 + jj2) * KC + k];
        tb += r2[(q * 4 + jj2) * KC + k];
      }
      float a = tanhf(ta + ba[j0 + jj2]);
      float g = 1.f / (1.f + expf(-(tb + bb_[j0 + jj2])));
      gate_sh[jj2 * KC + k] = a * g * Vc[j0 + jj2];  // bc dropped: shift-inv
    }
    __syncthreads();
    if (tid < KC) {
      float s = 0.f;
#pragma unroll
      for (int jj2 = 0; jj2 < 4; ++jj2) s += gate_sh[jj2 * KC + tid];
      sred[b * 16 + tid] = s;
    }
  }
  bar_arrive_wait(&bar[1]);

  // ---- stage 3: softmax over clusters + h_path + rho (4 j per block)
  if (tid < KC) {
    float s = 0.f;
    for (int q = 0; q < NTB; ++q) s += sred[q * 16 + tid];
    ws_sh[tid] = s;
  }
  __syncthreads();
  if (tid == 0) {
    float m = -1e30f;
#pragma unroll
    for (int k2 = 0; k2 < KC; ++k2) m = fmaxf(m, ws_sh[k2]);
    float Z = 0.f;
#pragma unroll
    for (int k2 = 0; k2 < KC; ++k2) {
      float e = expf(ws_sh[k2] - m);
      ws_sh[k2] = e;
      Z += e;
    }
    float iZ = 1.f / Z;
#pragma unroll
    for (int k2 = 0; k2 < KC; ++k2) ws_sh[k2] *= iZ;
  }
  __syncthreads();
#pragma unroll
  for (int it = 0; it < 2; ++it) {
    int d = it * 256 + tid;
    float s = 0.f;
#pragma unroll
    for (int k2 = 0; k2 < KC; ++k2) s = fmaf(ws_sh[k2], p_sh[k2 * DH + d], s);
    hp_sh[d] = s;
  }
  __syncthreads();
  {
    const int jj = tid & 3, dq = tid >> 2;
    const int j0 = b * 4;
    float acc = 0.f;
#pragma unroll 4
    for (int i = 0; i < 8; ++i) {
      int d = dq * 8 + i;
      acc = fmaf(hp_sh[d], rhoW[(size_t)d * DA + j0 + jj], acc);
    }
    r1[dq * 4 + jj] = acc;
    __syncthreads();
    if (tid < 4) {
      float s = 0.f;
#pragma unroll
      for (int q = 0; q < 64; ++q) s += r1[q * 4 + tid];
      h2g[j0 + tid] = fmaxf(s + rhob[j0 + tid], 0.f);
    }
  }

  // ---- stage 4: classifier (block 0 only; others arrive and exit)
  if (b != 0) {
    __syncthreads();
    if (tid == 0) {
      __threadfence();
      __hip_atomic_fetch_add(&bar[2], 1, __ATOMIC_RELEASE,
                             __HIP_MEMORY_SCOPE_AGENT);
    }
    return;
  }
  bar_arrive_wait(&bar[2]);
  {
    float h = h2g[tid];
#pragma unroll
    for (int c = 0; c < NCLS; ++c)
      r1[c * 256 + tid] = h * clsW[(size_t)tid * NCLS + c];
    __syncthreads();
    for (int s = 128; s > 0; s >>= 1) {
      if (tid < s) {
#pragma unroll
        for (int c = 0; c < NCLS; ++c)
          r1[c * 256 + tid] += r1[c * 256 + tid + s];
      }
      __syncthreads();
    }
    if (tid == 0) {
      float lg[NCLS], hz[NCLS];
      int best = 0;
#pragma unroll
      for (int c = 0; c < NCLS; ++c) {
        lg[c] = r1[c * 256] + clsb[c];
        hz[c] = 1.f / (1.f + expf(-lg[c]));
        if (lg[c] > lg[best]) best = c;
      }
      float S = 1.f;
#pragma unroll
      for (int c = 0; c < NCLS; ++c) out[c] = hz[c];
#pragma unroll
      for (int c = 0; c < NCLS; ++c) {
        S *= (1.f - hz[c]);
        out[NCLS + c] = S;
      }
      out[2 * NCLS] = (float)best;
    }
  }
}

extern "C" void kernel_launch(void* const* d_in, const int* in_sizes, int n_in,
                              void* d_out, int out_size, void* d_ws,
                              size_t ws_size, hipStream_t stream) {
  const float* x    = (const float*)d_in[0];
  const int*   cid  = (const int*)d_in[1];
  const float* W1   = (const float*)d_in[2];
  const float* b1   = (const float*)d_in[3];
  const float* W2   = (const float*)d_in[4];
  const float* b2   = (const float*)d_in[5];
  const float* fcW  = (const float*)d_in[6];
  const float* fcb  = (const float*)d_in[7];
  const float* Va   = (const float*)d_in[8];
  const float* ba   = (const float*)d_in[9];
  const float* Vb   = (const float*)d_in[10];
  const float* bb_  = (const float*)d_in[11];
  const float* Vc   = (const float*)d_in[12];
  const float* rhoW = (const float*)d_in[14];
  const float* rhob = (const float*)d_in[15];
  const float* clsW = (const float*)d_in[16];
  const float* clsb = (const float*)d_in[17];
  float* out = (float*)d_out;

  char* ws = (char*)d_ws;
  int*   cnt     = (int*)(ws + OFF_CNT);
  int*   bar     = (int*)(ws + OFF_BAR);
  int*   idxlist = (int*)(ws + OFF_IDX);
  float* psum    = (float*)(ws + OFF_PSUM);
  float* hstore  = (float*)(ws + OFF_H);
  float* h2g     = (float*)(ws + OFF_H2);
  float* sred    = (float*)(ws + OFF_SRED);
  u16*   W1p     = (u16*)(ws + OFF_W1P);
  u16*   W2p     = (u16*)(ws + OFF_W2P);

  (void)hipMemsetAsync(cnt, 0, 64, stream);  // cnt[10] + bar[3]
  prep_kernel<<<NB_PREP, 256, 0, stream>>>(cid, cnt, idxlist, W1, W2, W1p, W2p,
                                           psum);
  phi_kernel<<<512, 512, 0, stream>>>(x, W1p, W2p, b1, b2, cnt, idxlist, psum);
  tail_kernel<<<NTB, 256, 0, stream>>>(psum, cnt, fcW, fcb, Va, ba, Vb, bb_,
                                       Vc, rhoW, rhob, clsW, clsb, hstore,
                                       sred, h2g, bar, out);
}

// Round 11
// 183.315 us; speedup vs baseline: 2.2936x; 1.0979x over previous
//
#include <hip/hip_runtime.h>
#include <math.h>

// Problem constants (from reference)
#define NPATCH 8192
#define KC     10
#define DIN    1024
#define DH     512
#define DA     256
#define NCLS   4

#define TM  32    // patches per phi tile
#define LDA 520   // padded LDS row stride (u16)

typedef unsigned short u16;
typedef short bf16x8 __attribute__((ext_vector_type(8)));   // 8 bf16 = 4 VGPRs
typedef float f32x4  __attribute__((ext_vector_type(4)));

// Workspace layout (bytes)
#define OFF_CNT   0                  // int[KC] (40B)
#define OFF_BAR   48                 // int[3] spin-barrier counters (covered by 64B memset)
#define OFF_IDX   64                 // int[KC*NPATCH]
#define OFF_PSUM  327744             // float[KC*DH]
#define OFF_H     348224             // float[KC*DH]
#define OFF_H2    368768             // float[DA] (1KB)
#define OFF_SRED  369792             // float[64*16] per-block attn partials
#define OFF_W1P   373888             // u16[KC*DIN*DH] fragment-order panels
#define OFF_W2P   10859648           // u16[KC*DH*DH]  fragment-order panels
// total ~16 MB

__device__ __forceinline__ u16 f2bf(float f) {
  union { float f; unsigned u; } v; v.f = f;
  unsigned r = (v.u + 0x7fffu + ((v.u >> 16) & 1u)) >> 16;  // RNE
  return (u16)r;
}

// packed RNE f32x2 -> bf16x2 (low = lo)
__device__ __forceinline__ unsigned cvtpk(float lo, float hi) {
  unsigned r;
  asm("v_cvt_pk_bf16_f32 %0, %1, %2" : "=v"(r) : "v"(lo), "v"(hi));
  return r;
}

struct __align__(8) U16x4 { u16 x, y, z, w; };
union BF8U { bf16x8 v; unsigned u[4]; };

#define W1_TILES (KC * (DIN / 32) * (DH / 32))  // 5120
#define W2_TILES (KC * (DH / 32) * (DH / 32))   // 2560
#define NB_BUCKET 32
#define NB_PREP (NB_BUCKET + W1_TILES + W2_TILES)  // 7712

// Fused prep: bucket + zero psum (blocks 0..31), pack W1/W2 -> bf16 MFMA-B
// panels in FRAGMENT ORDER: within each 16-col x 32-ki chunk (1KB),
// u16 idx = (ki>>3)*128 + (col&15)*8 + (ki&7). A wave's bf16x8 fragment
// read is then lane-sequential (lane i at byte i*16) -> single 1KB
// coalesced transaction per load instead of a permuted 64-way walk.
__global__ __launch_bounds__(256) void prep_kernel(
    const int* __restrict__ cid, int* __restrict__ cnt,
    int* __restrict__ idxlist, const float* __restrict__ W1,
    const float* __restrict__ W2, u16* __restrict__ W1p,
    u16* __restrict__ W2p, float* __restrict__ psum) {
  int b = blockIdx.x, t = threadIdx.x;
  if (b < NB_BUCKET) {
    int g = b * 256 + t;
    if (g < KC * DH) psum[g] = 0.f;
    __shared__ int lcnt[KC], lbase[KC];
    if (t < KC) lcnt[t] = 0;
    __syncthreads();
    int n = b * 256 + t;                 // NPATCH == 32*256
    int k = cid[n];
    int myoff = atomicAdd(&lcnt[k], 1);
    __syncthreads();
    if (t < KC) lbase[t] = atomicAdd(&cnt[t], lcnt[t]);
    __syncthreads();
    idxlist[k * NPATCH + lbase[k] + myoff] = n;
  } else {
    __shared__ u16 tile[32][33];
    int bb = b - NB_BUCKET;
    const float* src;
    u16* dst;
    if (bb < W1_TILES) {
      int k = bb / 512, rem = bb % 512;
      int kb = rem / 16, n0 = (rem % 16) * 32;
      src = W1 + (size_t)k * DIN * DH + (size_t)kb * 32 * DH + n0;
      dst = W1p + (((size_t)(k * 32 + kb) * 512 + n0) * 32);
    } else {
      int b2 = bb - W1_TILES;
      int k = b2 / 256, rem = b2 % 256;
      int kb = rem / 16, n0 = (rem % 16) * 32;
      src = W2 + (size_t)k * DH * DH + (size_t)kb * 32 * DH + n0;
      dst = W2p + (((size_t)(k * 16 + kb) * 512 + n0) * 32);
    }
    {
      int ki = t >> 3, n4 = (t & 7) * 4;
      float4 v = *(const float4*)&src[(size_t)ki * DH + n4];
      tile[ki][n4 + 0] = f2bf(v.x);
      tile[ki][n4 + 1] = f2bf(v.y);
      tile[ki][n4 + 2] = f2bf(v.z);
      tile[ki][n4 + 3] = f2bf(v.w);
    }
    __syncthreads();
    {
      int n = t >> 3, ki = (t & 7) * 4;   // ki%4==0, so ki..ki+3 same 8-group
      U16x4 o = {tile[ki + 0][n], tile[ki + 1][n], tile[ki + 2][n],
                 tile[ki + 3][n]};
      // fragment-order index within the 32-col tile (2 chunks of 16 cols)
      size_t idx = (size_t)(n >> 4) * 512 + ((ki >> 3) * 128) +
                   ((n & 15) * 8) + (ki & 7);
      *(U16x4*)&dst[idx] = o;
    }
  }
}

// Fused phi: per 32-patch tile, layer1 (K=1024) -> relu/bf16 H in LDS ->
// layer2 (K=512) -> masked rowsum -> psum atomics. No h1 global round-trip.
// 512 thr (8 waves, wave owns 64 cols, acc 2m x 4nt). B-fragment reads are
// lane-sequential (fragment-order panels). Dynamic tile grab: XCD s=bid&7
// takes contiguous tile range [G*s/8, G*(s+1)/8).
__global__ __launch_bounds__(512, 4) void phi_kernel(
    const float* __restrict__ x, const u16* __restrict__ W1p,
    const u16* __restrict__ W2p, const float* __restrict__ b1,
    const float* __restrict__ b2, const int* __restrict__ cnt,
    const int* __restrict__ idxlist, float* __restrict__ psum) {
  __shared__ __align__(16) u16 A0[TM * LDA];   // 33.3 KB (x kh0, then H)
  __shared__ __align__(16) u16 A1[TM * LDA];   // 33.3 KB (x kh1)
  __shared__ int ridx[TM];

  const int tid = threadIdx.x;
  const int w = tid >> 6, lane = tid & 63;
  const int quad = lane >> 4, l16 = lane & 15;

  int cn[KC];
#pragma unroll
  for (int i = 0; i < KC; ++i) cn[i] = cnt[i];
  int G = 0;
#pragma unroll
  for (int i = 0; i < KC; ++i) G += (cn[i] + TM - 1) >> 5;

  const int s = blockIdx.x & 7, j = blockIdx.x >> 3;
  const int lo = (G * s) >> 3, hi = (G * (s + 1)) >> 3;

  for (int g = lo + j; g < hi; g += 64) {
    // locate (cluster kk, chunk rg) for global tile g — all-static indexing
    int kk = 0, rg = g, cntk = cn[0];
#pragma unroll
    for (int i = 0; i < KC - 1; ++i) {
      int nch = (cn[i] + TM - 1) >> 5;
      if (rg >= nch) { kk = i + 1; rg -= nch; cntk = cn[i + 1]; }
    }
    const int base = rg * TM;

    if (tid < TM)
      ridx[tid] = (base + tid < cntk) ? idxlist[kk * NPATCH + base + tid] : -1;
    __syncthreads();   // also guards LDS reuse across tile iterations

    // ---- stage x tile: 32 rows x 1024 cols bf16 into A0 (kh0) + A1 (kh1)
#pragma unroll
    for (int u8 = 0; u8 < 8; ++u8) {
      const int kh = u8 & 1;
      const int r = w * 4 + (u8 >> 1);
      int src = ridx[r];
      BF8U o;
      if (src >= 0) {
        const float4* xp =
            (const float4*)(x + (size_t)src * DIN + kh * 512 + lane * 8);
        float4 v0 = xp[0], v1 = xp[1];
        o.u[0] = cvtpk(v0.x, v0.y);
        o.u[1] = cvtpk(v0.z, v0.w);
        o.u[2] = cvtpk(v1.x, v1.y);
        o.u[3] = cvtpk(v1.z, v1.w);
      } else {
        o.u[0] = 0; o.u[1] = 0; o.u[2] = 0; o.u[3] = 0;
      }
      u16* dstbuf = kh ? A1 : A0;
      *(bf16x8*)&dstbuf[r * LDA + lane * 8] = o.v;
    }
    __syncthreads();

    // ---- layer1: acc[2][4] over K=1024 (two 512-halves from A0/A1)
    const f32x4 zero4 = {0.f, 0.f, 0.f, 0.f};
    f32x4 acc[2][4];
#pragma unroll
    for (int m = 0; m < 2; ++m)
#pragma unroll
      for (int nt = 0; nt < 4; ++nt) acc[m][nt] = zero4;

#pragma unroll
    for (int kh = 0; kh < 2; ++kh) {
      const u16* Abuf = kh ? A1 : A0;
      // fragment-order base: slab (kk*32+kh*16), wave chunk w*4, lane*8
      const u16* wb = W1p + (size_t)(kk * 32 + kh * 16) * 16384 + w * 2048 +
                      lane * 8;
      bf16x8 B[2][4];
#pragma unroll
      for (int nt = 0; nt < 4; ++nt)
        B[0][nt] = *(const bf16x8*)(wb + nt * 512);
#pragma unroll
      for (int ks = 0; ks < 16; ++ks) {
        const int cur = ks & 1, nxt = cur ^ 1;
        if (ks < 15) {
#pragma unroll
          for (int nt = 0; nt < 4; ++nt)
            B[nxt][nt] =
                *(const bf16x8*)(wb + (size_t)(ks + 1) * 16384 + nt * 512);
        }
        bf16x8 af0 = *(const bf16x8*)&Abuf[l16 * LDA + ks * 32 + quad * 8];
        bf16x8 af1 =
            *(const bf16x8*)&Abuf[(16 + l16) * LDA + ks * 32 + quad * 8];
#pragma unroll
        for (int nt = 0; nt < 4; ++nt) {
          acc[0][nt] = __builtin_amdgcn_mfma_f32_16x16x32_bf16(
              af0, B[cur][nt], acc[0][nt], 0, 0, 0);
          acc[1][nt] = __builtin_amdgcn_mfma_f32_16x16x32_bf16(
              af1, B[cur][nt], acc[1][nt], 0, 0, 0);
        }
      }
    }
    __syncthreads();   // all waves done reading A0/A1

    // ---- H = relu(acc + b1) -> bf16 into A0
#pragma unroll
    for (int m = 0; m < 2; ++m)
#pragma unroll
      for (int nt = 0; nt < 4; ++nt) {
        int c = w * 64 + nt * 16 + l16;
        float bias = b1[kk * DH + c];
#pragma unroll
        for (int r = 0; r < 4; ++r) {
          int row = m * 16 + quad * 4 + r;
          A0[row * LDA + c] = f2bf(fmaxf(acc[m][nt][r] + bias, 0.f));
        }
      }
    __syncthreads();

    // ---- layer2: acc2[2][4] over K=512 from H (A0)
    f32x4 acc2[2][4];
#pragma unroll
    for (int m = 0; m < 2; ++m)
#pragma unroll
      for (int nt = 0; nt < 4; ++nt) acc2[m][nt] = zero4;

    {
      const u16* wb2 = W2p + (size_t)(kk * 16) * 16384 + w * 2048 + lane * 8;
      bf16x8 B[2][4];
#pragma unroll
      for (int nt = 0; nt < 4; ++nt)
        B[0][nt] = *(const bf16x8*)(wb2 + nt * 512);
#pragma unroll
      for (int ks = 0; ks < 16; ++ks) {
        const int cur = ks & 1, nxt = cur ^ 1;
        if (ks < 15) {
#pragma unroll
          for (int nt = 0; nt < 4; ++nt)
            B[nxt][nt] =
                *(const bf16x8*)(wb2 + (size_t)(ks + 1) * 16384 + nt * 512);
        }
        bf16x8 af0 = *(const bf16x8*)&A0[l16 * LDA + ks * 32 + quad * 8];
        bf16x8 af1 =
            *(const bf16x8*)&A0[(16 + l16) * LDA + ks * 32 + quad * 8];
#pragma unroll
        for (int nt = 0; nt < 4; ++nt) {
          acc2[0][nt] = __builtin_amdgcn_mfma_f32_16x16x32_bf16(
              af0, B[cur][nt], acc2[0][nt], 0, 0, 0);
          acc2[1][nt] = __builtin_amdgcn_mfma_f32_16x16x32_bf16(
              af1, B[cur][nt], acc2[1][nt], 0, 0, 0);
        }
      }
    }

    // ---- masked mean-pool numerator -> psum atomics
    float vmask[2][4];
#pragma unroll
    for (int m = 0; m < 2; ++m)
#pragma unroll
      for (int r = 0; r < 4; ++r)
        vmask[m][r] = (base + m * 16 + quad * 4 + r < cntk) ? 1.f : 0.f;

#pragma unroll
    for (int nt = 0; nt < 4; ++nt) {
      int col = w * 64 + nt * 16 + l16;
      float bias = b2[kk * DH + col];
      float sv = 0.f;
#pragma unroll
      for (int m = 0; m < 2; ++m)
#pragma unroll
        for (int r = 0; r < 4; ++r)
          sv += vmask[m][r] * fmaxf(acc2[m][nt][r] + bias, 0.f);
      sv += __shfl_xor(sv, 16, 64);
      sv += __shfl_xor(sv, 32, 64);
      if (quad == 0) atomicAdd(&psum[kk * DH + col], sv);
    }
  }
}

// ---------------------------------------------------------------------------
// Fused tail: fc + gated-attn + softmax + rho + classifier in ONE kernel.
// 64 blocks x 256 threads, device-scope spin barriers between stages.
#define NTB 64

__device__ __forceinline__ void bar_arrive_wait(int* bar) {
  __syncthreads();
  if (threadIdx.x == 0) {
    __threadfence();
    __hip_atomic_fetch_add(bar, 1, __ATOMIC_RELEASE, __HIP_MEMORY_SCOPE_AGENT);
    while (__hip_atomic_load(bar, __ATOMIC_ACQUIRE,
                             __HIP_MEMORY_SCOPE_AGENT) < NTB) {
      __builtin_amdgcn_s_sleep(1);
    }
  }
  __syncthreads();
}

__global__ __launch_bounds__(256) void tail_kernel(
    const float* __restrict__ psum, const int* __restrict__ cnt,
    const float* __restrict__ fcW, const float* __restrict__ fcb,
    const float* __restrict__ Va, const float* __restrict__ ba,
    const float* __restrict__ Vb, const float* __restrict__ bb_,
    const float* __restrict__ Vc, const float* __restrict__ rhoW,
    const float* __restrict__ rhob, const float* __restrict__ clsW,
    const float* __restrict__ clsb, float* __restrict__ hstore,
    float* __restrict__ sred, float* __restrict__ h2g,
    int* __restrict__ bar, float* __restrict__ out) {
  __shared__ float p_sh[KC * DH];      // 20 KB (pooled feats, then hstore)
  __shared__ float r1[2560];           // 10 KB
  __shared__ float r2[2560];           // 10 KB
  __shared__ float invs[KC];
  __shared__ float gate_sh[4 * KC];
  __shared__ float ws_sh[KC];
  __shared__ float hp_sh[DH];
  const int tid = threadIdx.x;
  const int b = blockIdx.x;

  // ---- stage 1: fc — hstore[k][j] for j in [b*8, b*8+8)
  if (tid < KC) {
    int c = cnt[tid];
    invs[tid] = (c > 0) ? 1.f / (float)c : 0.f;
  }
  __syncthreads();
#pragma unroll
  for (int it = 0; it < KC * DH / 256; ++it) {
    int e = it * 256 + tid;
    p_sh[e] = psum[e] * invs[e >> 9];
  }
  __syncthreads();
  {
    const int jj = tid & 7, dq = tid >> 3;   // 8 j x 32 d-chunks of 16
    const int j0 = b * 8;
    float acc[KC];
#pragma unroll
    for (int k = 0; k < KC; ++k) acc[k] = 0.f;
#pragma unroll 4
    for (int i = 0; i < 16; ++i) {
      int d = dq * 16 + i;
      float wv = fcW[(size_t)d * DH + j0 + jj];
#pragma unroll
      for (int k = 0; k < KC; ++k) acc[k] = fmaf(p_sh[k * DH + d], wv, acc[k]);
    }
#pragma unroll
    for (int k = 0; k < KC; ++k) r1[(dq * 8 + jj) * KC + k] = acc[k];
    __syncthreads();
    if (tid < 8 * KC) {
      int jj2 = tid / KC, k = tid % KC;
      float s = 0.f;
#pragma unroll
      for (int q = 0; q < 32; ++q) s += r1[(q * 8 + jj2) * KC + k];
      hstore[k * DH + j0 + jj2] = fmaxf(s + fcb[j0 + jj2], 0.f);
    }
  }
  bar_arrive_wait(&bar[0]);

  // ---- stage 2: gated attention partials — 4 j per block
#pragma unroll
  for (int it = 0; it < KC * DH / 256; ++it) {
    int e = it * 256 + tid;
    p_sh[e] = hstore[e];
  }
  __syncthreads();
  {
    const int jj = tid & 3, dq = tid >> 2;   // 4 j x 64 d-chunks of 8
    const int j0 = b * 4;
    float sa[KC], sb[KC];
#pragma unroll
    for (int k = 0; k < KC; ++k) { sa[k] = 0.f; sb[k] = 0.f; }
#pragma unroll 4
    for (int i = 0; i < 8; ++i) {
      int d = dq * 8 + i;
      float va = Va[(size_t)d * DA + j0 + jj];
      float vb = Vb[(size_t)d * DA + j0 + jj];
#pragma unroll
      for (int k = 0; k < KC; ++k) {
        float h = p_sh[k * DH + d];
        sa[k] = fmaf(h, va, sa[k]);
        sb[k] = fmaf(h, vb, sb[k]);
      }
    }
#pragma unroll
    for (int k = 0; k < KC; ++k) {
      r1[(dq * 4 + jj) * KC + k] = sa[k];
      r2[(dq * 4 + jj) * KC + k] = sb[k];
    }
    __syncthreads();
    if (tid < 4 * KC) {
      int jj2 = tid / KC, k = tid % KC;
      float ta = 0.f, tb = 0.f;
#pragma unroll
      for (int q = 0; q < 64; ++q) {
        ta += r1[(q * 4 + jj2) * KC + k];
        tb += r2[(q * 4 + jj2) * KC + k];
      }
      float a = tanhf(ta + ba[j0 + jj2]);
      float g = 1.f / (1.f + expf(-(tb + bb_[j0 + jj2])));
      gate_sh[jj2 * KC + k] = a * g * Vc[j0 + jj2];  // bc dropped: shift-inv
    }
    __syncthreads();
    if (tid < KC) {
      float s = 0.f;
#pragma unroll
      for (int jj2 = 0; jj2 < 4; ++jj2) s += gate_sh[jj2 * KC + tid];
      sred[b * 16 + tid] = s;
    }
  }
  bar_arrive_wait(&bar[1]);

  // ---- stage 3: softmax over clusters + h_path + rho (4 j per block)
  if (tid < KC) {
    float s = 0.f;
    for (int q = 0; q < NTB; ++q) s += sred[q * 16 + tid];
    ws_sh[tid] = s;
  }
  __syncthreads();
  if (tid == 0) {
    float m = -1e30f;
#pragma unroll
    for (int k2 = 0; k2 < KC; ++k2) m = fmaxf(m, ws_sh[k2]);
    float Z = 0.f;
#pragma unroll
    for (int k2 = 0; k2 < KC; ++k2) {
      float e = expf(ws_sh[k2] - m);
      ws_sh[k2] = e;
      Z += e;
    }
    float iZ = 1.f / Z;
#pragma unroll
    for (int k2 = 0; k2 < KC; ++k2) ws_sh[k2] *= iZ;
  }
  __syncthreads();
#pragma unroll
  for (int it = 0; it < 2; ++it) {
    int d = it * 256 + tid;
    float s = 0.f;
#pragma unroll
    for (int k2 = 0; k2 < KC; ++k2) s = fmaf(ws_sh[k2], p_sh[k2 * DH + d], s);
    hp_sh[d] = s;
  }
  __syncthreads();
  {
    const int jj = tid & 3, dq = tid >> 2;
    const int j0 = b * 4;
    float acc = 0.f;
#pragma unroll 4
    for (int i = 0; i < 8; ++i) {
      int d = dq * 8 + i;
      acc = fmaf(hp_sh[d], rhoW[(size_t)d * DA + j0 + jj], acc);
    }
    r1[dq * 4 + jj] = acc;
    __syncthreads();
    if (tid < 4) {
      float s = 0.f;
#pragma unroll
      for (int q = 0; q < 64; ++q) s += r1[q * 4 + tid];
      h2g[j0 + tid] = fmaxf(s + rhob[j0 + tid], 0.f);
    }
  }

  // ---- stage 4: classifier (block 0 only; others arrive and exit)
  if (b != 0) {
    __syncthreads();
    if (tid == 0) {
      __threadfence();
      __hip_atomic_fetch_add(&bar[2], 1, __ATOMIC_RELEASE,
                             __HIP_MEMORY_SCOPE_AGENT);
    }
    return;
  }
  bar_arrive_wait(&bar[2]);
  {
    float h = h2g[tid];
#pragma unroll
    for (int c = 0; c < NCLS; ++c)
      r1[c * 256 + tid] = h * clsW[(size_t)tid * NCLS + c];
    __syncthreads();
    for (int s = 128; s > 0; s >>= 1) {
      if (tid < s) {
#pragma unroll
        for (int c = 0; c < NCLS; ++c)
          r1[c * 256 + tid] += r1[c * 256 + tid + s];
      }
      __syncthreads();
    }
    if (tid == 0) {
      float lg[NCLS], hz[NCLS];
      int best = 0;
#pragma unroll
      for (int c = 0; c < NCLS; ++c) {
        lg[c] = r1[c * 256] + clsb[c];
        hz[c] = 1.f / (1.f + expf(-lg[c]));
        if (lg[c] > lg[best]) best = c;
      }
      float S = 1.f;
#pragma unroll
      for (int c = 0; c < NCLS; ++c) out[c] = hz[c];
#pragma unroll
      for (int c = 0; c < NCLS; ++c) {
        S *= (1.f - hz[c]);
        out[NCLS + c] = S;
      }
      out[2 * NCLS] = (float)best;
    }
  }
}

extern "C" void kernel_launch(void* const* d_in, const int* in_sizes, int n_in,
                              void* d_out, int out_size, void* d_ws,
                              size_t ws_size, hipStream_t stream) {
  const float* x    = (const float*)d_in[0];
  const int*   cid  = (const int*)d_in[1];
  const float* W1   = (const float*)d_in[2];
  const float* b1   = (const float*)d_in[3];
  const float* W2   = (const float*)d_in[4];
  const float* b2   = (const float*)d_in[5];
  const float* fcW  = (const float*)d_in[6];
  const float* fcb  = (const float*)d_in[7];
  const float* Va   = (const float*)d_in[8];
  const float* ba   = (const float*)d_in[9];
  const float* Vb   = (const float*)d_in[10];
  const float* bb_  = (const float*)d_in[11];
  const float* Vc   = (const float*)d_in[12];
  const float* rhoW = (const float*)d_in[14];
  const float* rhob = (const float*)d_in[15];
  const float* clsW = (const float*)d_in[16];
  const float* clsb = (const float*)d_in[17];
  float* out = (float*)d_out;

  char* ws = (char*)d_ws;
  int*   cnt     = (int*)(ws + OFF_CNT);
  int*   bar     = (int*)(ws + OFF_BAR);
  int*   idxlist = (int*)(ws + OFF_IDX);
  float* psum    = (float*)(ws + OFF_PSUM);
  float* hstore  = (float*)(ws + OFF_H);
  float* h2g     = (float*)(ws + OFF_H2);
  float* sred    = (float*)(ws + OFF_SRED);
  u16*   W1p     = (u16*)(ws + OFF_W1P);
  u16*   W2p     = (u16*)(ws + OFF_W2P);

  (void)hipMemsetAsync(cnt, 0, 64, stream);  // cnt[10] + bar[3]
  prep_kernel<<<NB_PREP, 256, 0, stream>>>(cid, cnt, idxlist, W1, W2, W1p, W2p,
                                           psum);
  phi_kernel<<<512, 512, 0, stream>>>(x, W1p, W2p, b1, b2, cnt, idxlist, psum);
  tail_kernel<<<NTB, 256, 0, stream>>>(psum, cnt, fcW, fcb, Va, ba, Vb, bb_,
                                       Vc, rhoW, rhob, clsW, clsb, hstore,
                                       sred, h2g, bar, out);
}